// Round 5
// baseline (241.025 us; speedup 1.0000x reference)
//
#include <hip/hip_runtime.h>

// Problem constants
#define BB 4
#define NN 65536
#define CC 256
#define KK 4096
#define MIDC 128

// ============ Kernel 1: fused score + exact top-K per batch, all in LDS ============
// 13-bit bins (sign+exp+4 mantissa) of the order-preserving key map. Histogram ->
// threshold bin + per-bin rankbase; candidates compacted grouped-by-bin; exact
// within-bin rank via 8-way-unrolled LDS broadcast loop (lanes in a wave share a
// bin -> same-address reads broadcast). Composite key64=(key32<<32)|~n all distinct;
// descending key64 == jax.lax.top_k order (desc score, asc index on ties).
#define BINS 8192
#define SELC 8192
__global__ __launch_bounds__(1024) void select_kernel(const float* __restrict__ cls,
                                                      int* __restrict__ idxout) {
    __shared__ unsigned hist[BINS];            // becomes rankbase in-place
    __shared__ unsigned cnt[BINS];
    __shared__ unsigned long long sel[SELC];
    __shared__ unsigned ts[1024];
    __shared__ int tinfo[2];

    int b = blockIdx.x;
    int t = threadIdx.x;
    const float4* cb4 = reinterpret_cast<const float4*>(cls + (size_t)b * NN * 3);

    for (int i = t; i < BINS; i += 1024) { hist[i] = 0u; cnt[i] = 0u; }
    __syncthreads();

    // P1: keys (4 points/thread/iter, float4 loads) -> histogram
    for (int it = 0; it < 16; ++it) {
        int fb = it * 3072 + t * 3;
        float4 v0 = cb4[fb], v1 = cb4[fb + 1], v2 = cb4[fb + 2];
        float m[4];
        m[0] = fmaxf(fmaxf(v0.x, v0.y), v0.z);
        m[1] = fmaxf(fmaxf(v0.w, v1.x), v1.y);
        m[2] = fmaxf(fmaxf(v1.z, v1.w), v2.x);
        m[3] = fmaxf(fmaxf(v2.y, v2.z), v2.w);
#pragma unroll
        for (int j = 0; j < 4; j++) {
            unsigned u = __float_as_uint(m[j]);
            u = (u & 0x80000000u) ? ~u : (u | 0x80000000u);
            atomicAdd(&hist[u >> 19], 1u);
        }
    }
    __syncthreads();

    // P2: suffix scan (8 contiguous bins/thread) -> rankbase in-place + threshold
    int base = t * 8;
    unsigned hloc[8];
    unsigned s8 = 0;
#pragma unroll
    for (int i = 0; i < 8; i++) { hloc[i] = hist[base + i]; s8 += hloc[i]; }
    ts[t] = s8;
    __syncthreads();
    for (int off = 1; off < 1024; off <<= 1) {
        unsigned v = ts[t] + ((t + off) < 1024 ? ts[t + off] : 0u);
        __syncthreads();
        ts[t] = v;
        __syncthreads();
    }
    unsigned above = ts[t] - s8;               // keys in bins owned by threads > t
#pragma unroll
    for (int i = 7; i >= 0; i--) {
        unsigned h = hloc[i];
        hist[base + i] = above;                // rankbase (in-place overwrite)
        if ((int)above < KK && (int)(above + h) >= KK) {
            tinfo[0] = base + i;
            tinfo[1] = (int)(above + h);       // total candidates
        }
        above += h;
    }
    __syncthreads();
    int tbin = tinfo[0];

    // P3: recompute keys, compact candidates grouped by bin
    for (int it = 0; it < 16; ++it) {
        int fb = it * 3072 + t * 3;
        float4 v0 = cb4[fb], v1 = cb4[fb + 1], v2 = cb4[fb + 2];
        float m[4];
        m[0] = fmaxf(fmaxf(v0.x, v0.y), v0.z);
        m[1] = fmaxf(fmaxf(v0.w, v1.x), v1.y);
        m[2] = fmaxf(fmaxf(v1.z, v1.w), v2.x);
        m[3] = fmaxf(fmaxf(v2.y, v2.z), v2.w);
#pragma unroll
        for (int j = 0; j < 4; j++) {
            unsigned u = __float_as_uint(m[j]);
            u = (u & 0x80000000u) ? ~u : (u | 0x80000000u);
            int bin = (int)(u >> 19);
            if (bin >= tbin) {
                unsigned slot = hist[bin] + atomicAdd(&cnt[bin], 1u);
                if (slot < SELC) {
                    int n = it * 4096 + t * 4 + j;
                    sel[slot] = ((unsigned long long)u << 32) | (unsigned)(~n);
                }
            }
        }
    }
    __syncthreads();

    // P4: exact within-bin rank via 8-way unrolled broadcast loop
    int total = min(tinfo[1], SELC);
    for (int s_ = t; s_ < total; s_ += 1024) {
        unsigned long long key = sel[s_];
        int bin = (int)(key >> 51);
        unsigned sbase = hist[bin];
        unsigned c = min(cnt[bin], (unsigned)SELC - sbase);
        unsigned bigger = 0;
        unsigned j = 0;
        for (; j + 8 <= c; j += 8) {
            unsigned long long k0 = sel[sbase + j + 0];
            unsigned long long k1 = sel[sbase + j + 1];
            unsigned long long k2 = sel[sbase + j + 2];
            unsigned long long k3 = sel[sbase + j + 3];
            unsigned long long k4 = sel[sbase + j + 4];
            unsigned long long k5 = sel[sbase + j + 5];
            unsigned long long k6 = sel[sbase + j + 6];
            unsigned long long k7 = sel[sbase + j + 7];
            bigger += (k0 > key) + (k1 > key) + (k2 > key) + (k3 > key)
                    + (k4 > key) + (k5 > key) + (k6 > key) + (k7 > key);
        }
        for (; j < c; ++j) bigger += (sel[sbase + j] > key) ? 1u : 0u;
        unsigned pos = sbase + bigger;
        if (pos < KK) idxout[b * KK + pos] = (int)(~(unsigned)key);
    }
}

// ============ Kernel 2: gather + GEMM1 (C->MID) + BN partials + origins ============
#define KT 32
__global__ __launch_bounds__(256) void gemm1_kernel(const float* __restrict__ feats,
                                                    const float* __restrict__ points,
                                                    const float* __restrict__ w1,
                                                    const int* __restrict__ idx,
                                                    float* __restrict__ h_out,
                                                    float* __restrict__ psum,
                                                    float* __restrict__ psq,
                                                    float* __restrict__ outOrig) {
    __shared__ __align__(16) float w1s[MIDC][68];   // 34.8 KB
    __shared__ __align__(16) float fs[KT][68];      // 8.7 KB
    __shared__ int kidx[KT];
    __shared__ float redS[8][MIDC];                 // 4 KB
    __shared__ float redQ[8][MIDC];                 // 4 KB

    int t = threadIdx.x;
    int b = blockIdx.x >> 7;                  // K/KT = 128 tiles per batch
    int k0 = (blockIdx.x & 127) * KT;

    if (t < KT) kidx[t] = idx[b * KK + k0 + t];
    __syncthreads();

    if (t < KT * 3) {                         // gather origins
        int k = t / 3, o = t % 3;
        outOrig[(size_t)(b * KK + k0 + k) * 3 + o] =
            points[((size_t)b * NN + kidx[k]) * 3 + o];
    }

    int tm = t & 31;        // 32 m-groups, m = tm + 32*j
    int tk = t >> 5;        // 8 k-groups,  k = tk + 8*i
    float acc[4][4] = {};

    for (int c0 = 0; c0 < CC; c0 += 64) {
        for (int e = t; e < MIDC * 64; e += 256) {       // stage w1 chunk (coalesced)
            int m = e >> 6, c = e & 63;
            w1s[m][c] = w1[m * CC + c0 + c];
        }
        for (int e = t; e < KT * 64; e += 256) {         // gather feats chunk
            int k = e & 31, c = e >> 5;
            fs[k][c] = feats[((size_t)b * CC + c0 + c) * NN + kidx[k]];
        }
        __syncthreads();
#pragma unroll
        for (int c = 0; c < 64; c += 4) {
            float4 av[4], wv[4];
#pragma unroll
            for (int i = 0; i < 4; i++) av[i] = *reinterpret_cast<const float4*>(&fs[tk + 8 * i][c]);
#pragma unroll
            for (int j = 0; j < 4; j++) wv[j] = *reinterpret_cast<const float4*>(&w1s[tm + 32 * j][c]);
#pragma unroll
            for (int i = 0; i < 4; i++)
#pragma unroll
                for (int j = 0; j < 4; j++) {
                    acc[i][j] += av[i].x * wv[j].x;
                    acc[i][j] += av[i].y * wv[j].y;
                    acc[i][j] += av[i].z * wv[j].z;
                    acc[i][j] += av[i].w * wv[j].w;
                }
        }
        __syncthreads();
    }

    // write h + per-thread BN partials
    float ps[4] = {}, pq[4] = {};
#pragma unroll
    for (int i = 0; i < 4; i++) {
        int k = tk + 8 * i;
#pragma unroll
        for (int j = 0; j < 4; j++) {
            int m = tm + 32 * j;
            float v = acc[i][j];
            h_out[(size_t)(b * KK + k0 + k) * MIDC + m] = v;
            ps[j] += v;
            pq[j] += v * v;
        }
    }
#pragma unroll
    for (int j = 0; j < 4; j++) { redS[tk][tm + 32 * j] = ps[j]; redQ[tk][tm + 32 * j] = pq[j]; }
    __syncthreads();
    if (t < MIDC) {
        float s = 0.f, q = 0.f;
#pragma unroll
        for (int r = 0; r < 8; r++) { s += redS[r][t]; q += redQ[r][t]; }
        psum[blockIdx.x * MIDC + t] = s;
        psq[blockIdx.x * MIDC + t] = q;
    }
}

// ============ Kernel 3: finalize BN stats -> scale/bias ============
__global__ __launch_bounds__(512) void bnstat_kernel(const float* __restrict__ psum,
                                                     const float* __restrict__ psq,
                                                     const float* __restrict__ gamma,
                                                     const float* __restrict__ beta,
                                                     float* __restrict__ sb) {
    __shared__ float rs[4][MIDC];
    __shared__ float rq[4][MIDC];
    int m = threadIdx.x & 127, g = threadIdx.x >> 7;
    float s = 0.f, q = 0.f;
    for (int blk = g; blk < 512; blk += 4) {
        s += psum[blk * MIDC + m];
        q += psq[blk * MIDC + m];
    }
    rs[g][m] = s; rq[g][m] = q;
    __syncthreads();
    if (threadIdx.x < MIDC) {
        float S = rs[0][m] + rs[1][m] + rs[2][m] + rs[3][m];
        float Q = rq[0][m] + rq[1][m] + rq[2][m] + rq[3][m];
        const float inv = 1.0f / (float)(BB * KK);
        float mean = S * inv;
        float var = Q * inv - mean * mean;
        float scale = gamma[m] * rsqrtf(var + 1e-5f);
        sb[m] = scale;
        sb[MIDC + m] = beta[m] - mean * scale;
    }
}

// ============ Kernel 4: BN+ReLU+GEMM2(128->3)+clamp+add ============
__global__ __launch_bounds__(256) void out_kernel(const float* __restrict__ h,
                                                  const float* __restrict__ sb,
                                                  const float* __restrict__ w2,
                                                  const float* __restrict__ lim,
                                                  const float* __restrict__ orig,
                                                  float* __restrict__ preds,
                                                  float* __restrict__ offs) {
    int tid = blockIdx.x * 256 + threadIdx.x;
    int bk = tid >> 6;                // one wave per (b,k)
    int lane = tid & 63;
    const float* hp = h + (size_t)bk * MIDC;
    float h0 = hp[lane], h1 = hp[lane + 64];
    float y0 = fmaxf(h0 * sb[lane] + sb[MIDC + lane], 0.0f);
    float y1 = fmaxf(h1 * sb[lane + 64] + sb[MIDC + 64 + lane], 0.0f);
    float p0 = y0 * w2[lane]       + y1 * w2[lane + 64];
    float p1 = y0 * w2[128 + lane] + y1 * w2[192 + lane];
    float p2 = y0 * w2[256 + lane] + y1 * w2[320 + lane];
#pragma unroll
    for (int off = 32; off > 0; off >>= 1) {
        p0 += __shfl_xor(p0, off);
        p1 += __shfl_xor(p1, off);
        p2 += __shfl_xor(p2, off);
    }
    if (lane < 3) {
        float o = (lane == 0) ? p0 : ((lane == 1) ? p1 : p2);
        float L = lim[lane];
        float limited = fminf(fmaxf(o, -L), L);
        preds[bk * 3 + lane] = orig[bk * 3 + lane] + limited;
        offs[bk * 3 + lane] = o;
    }
}

// ============ launch ============
extern "C" void kernel_launch(void* const* d_in, const int* in_sizes, int n_in,
                              void* d_out, int out_size, void* d_ws, size_t ws_size,
                              hipStream_t stream) {
    const float* points   = (const float*)d_in[0];
    const float* features = (const float*)d_in[1];
    const float* cls      = (const float*)d_in[2];
    const float* w1       = (const float*)d_in[3];
    const float* gamma    = (const float*)d_in[4];
    const float* beta     = (const float*)d_in[5];
    const float* w2       = (const float*)d_in[6];
    const float* lim      = (const float*)d_in[7];

    float* out   = (float*)d_out;
    float* preds = out;                       // (B,K,3)
    float* orig  = out + BB * KK * 3;         // (B,K,3)
    float* offs  = out + 2 * BB * KK * 3;     // (B,K,3)

    float* wsf = (float*)d_ws;
    int*   idxw = (int*)wsf;                               // B*K
    float* h    = wsf + BB * KK;                           // B*K*MID
    float* psum = h + (size_t)BB * KK * MIDC;              // 512*MID
    float* psq  = psum + 512 * MIDC;                       // 512*MID
    float* sb   = psq + 512 * MIDC;                        // 2*MID

    select_kernel<<<BB, 1024, 0, stream>>>(cls, idxw);
    gemm1_kernel<<<BB * (KK / KT), 256, 0, stream>>>(features, points, w1, idxw, h, psum, psq, orig);
    bnstat_kernel<<<1, 512, 0, stream>>>(psum, psq, gamma, beta, sb);
    out_kernel<<<(BB * KK * 64) / 256, 256, 0, stream>>>(h, sb, w2, lim, orig, preds, offs);
}

// Round 6
// 169.999 us; speedup vs baseline: 1.4178x; 1.4178x over previous
//
#include <hip/hip_runtime.h>

// Problem constants
#define BB 4
#define NN 65536
#define CC 256
#define KK 4096
#define MIDC 128

// ============ Kernel 1: fused score + exact top-K per batch, all in LDS ============
// 15-bit fine bins (sign+8exp+6mant of the order-preserving key map), packed 2xu16
// per u32 word (64KB LDS). Histogram -> threshold bin + rankbase window; candidates
// compacted grouped-by-bin; exact within-bin rank via 8-way-unrolled LDS broadcast
// loop (lanes of a wave share a bin -> same-address reads broadcast, free).
// Composite key64=(key32<<32)|~n all distinct; descending key64 == jax.lax.top_k
// order (desc score, asc index on ties). Bins >= tbin+WIN-1 merge into one group;
// merging only grows c -- rank uses full key64 compares, so order stays exact.
#define FW 16384      // u32 words = 32768 fine bins
#define WIN 4096      // rankbase/cnt window above threshold bin
#define SELC 6144     // candidate buffer (~4096 + threshold-bin ~200)
__global__ __launch_bounds__(1024) void select_kernel(const float* __restrict__ cls,
                                                      int* __restrict__ idxout) {
    __shared__ unsigned hist32[FW];            // 64 KB
    __shared__ unsigned long long sel[SELC];   // 48 KB
    __shared__ unsigned rb[WIN];               // 16 KB
    __shared__ unsigned cnt[WIN];              // 16 KB
    __shared__ unsigned ts[1024];              // 4 KB
    __shared__ int tinfo[2];

    int b = blockIdx.x;
    int t = threadIdx.x;
    const float4* cb4 = reinterpret_cast<const float4*>(cls + (size_t)b * NN * 3);

    for (int i = t; i < FW; i += 1024) hist32[i] = 0u;
    for (int i = t; i < WIN; i += 1024) { rb[i] = 0u; cnt[i] = 0u; }
    __syncthreads();

    // P1: keys (4 points/thread/iter, float4 loads) -> packed u16 histogram
    for (int it = 0; it < 16; ++it) {
        int fb = it * 3072 + t * 3;
        float4 v0 = cb4[fb], v1 = cb4[fb + 1], v2 = cb4[fb + 2];
        float m[4];
        m[0] = fmaxf(fmaxf(v0.x, v0.y), v0.z);
        m[1] = fmaxf(fmaxf(v0.w, v1.x), v1.y);
        m[2] = fmaxf(fmaxf(v1.z, v1.w), v2.x);
        m[3] = fmaxf(fmaxf(v2.y, v2.z), v2.w);
#pragma unroll
        for (int j = 0; j < 4; j++) {
            unsigned u = __float_as_uint(m[j]);
            u = (u & 0x80000000u) ? ~u : (u | 0x80000000u);
            atomicAdd(&hist32[u >> 18], ((u >> 17) & 1u) ? 0x10000u : 1u);
        }
    }
    __syncthreads();

    // P2a: unpack 32 fine-bin counts/thread, suffix scan -> threshold bin
    unsigned hloc[32];
    int base = t * 16;
    unsigned s32 = 0;
#pragma unroll
    for (int w = 0; w < 16; w++) {
        unsigned word = hist32[base + w];
        hloc[2 * w] = word & 0xFFFFu;
        hloc[2 * w + 1] = word >> 16;
        s32 += (word & 0xFFFFu) + (word >> 16);
    }
    ts[t] = s32;
    __syncthreads();
    for (int off = 1; off < 1024; off <<= 1) {
        unsigned v = ts[t] + ((t + off) < 1024 ? ts[t + off] : 0u);
        __syncthreads();
        ts[t] = v;
        __syncthreads();
    }
    {
        unsigned above = ts[t] - s32;          // keys in bins owned by threads > t
#pragma unroll
        for (int i = 31; i >= 0; i--) {
            unsigned h = hloc[i];
            if ((int)above < KK && (int)(above + h) >= KK) {
                tinfo[0] = t * 32 + i;
                tinfo[1] = (int)(above + h);   // total candidates
            }
            above += h;
        }
    }
    __syncthreads();
    int tbin = tinfo[0];

    // P2b: write rankbase for window bins [tbin, tbin+WIN-1); rb[WIN-1]=0 (merged top)
    {
        unsigned above = ts[t] - s32;
#pragma unroll
        for (int i = 31; i >= 0; i--) {
            int bin = t * 32 + i;
            int off = bin - tbin;
            if (off >= 0 && off < WIN - 1) rb[off] = above;
            above += hloc[i];
        }
    }
    __syncthreads();

    // P3: recompute keys, compact candidates grouped by (windowed) bin
    for (int it = 0; it < 16; ++it) {
        int fb = it * 3072 + t * 3;
        float4 v0 = cb4[fb], v1 = cb4[fb + 1], v2 = cb4[fb + 2];
        float m[4];
        m[0] = fmaxf(fmaxf(v0.x, v0.y), v0.z);
        m[1] = fmaxf(fmaxf(v0.w, v1.x), v1.y);
        m[2] = fmaxf(fmaxf(v1.z, v1.w), v2.x);
        m[3] = fmaxf(fmaxf(v2.y, v2.z), v2.w);
#pragma unroll
        for (int j = 0; j < 4; j++) {
            unsigned u = __float_as_uint(m[j]);
            u = (u & 0x80000000u) ? ~u : (u | 0x80000000u);
            int off = (int)(u >> 17) - tbin;
            if (off >= 0) {
                if (off > WIN - 1) off = WIN - 1;
                unsigned slot = rb[off] + atomicAdd(&cnt[off], 1u);
                if (slot < SELC) {
                    int n = it * 4096 + t * 4 + j;
                    sel[slot] = ((unsigned long long)u << 32) | (unsigned)(~n);
                }
            }
        }
    }
    __syncthreads();

    // P4: exact within-bin rank via 8-way unrolled broadcast loop -> emit
    int total = min(tinfo[1], SELC);
    for (int s_ = t; s_ < total; s_ += 1024) {
        unsigned long long key = sel[s_];
        int off = (int)(key >> 49) - tbin;
        if (off > WIN - 1) off = WIN - 1;
        unsigned sbase = rb[off];
        unsigned c = min(cnt[off], (unsigned)SELC - sbase);
        unsigned bigger = 0;
        unsigned j = 0;
        for (; j + 8 <= c; j += 8) {
            unsigned long long k0 = sel[sbase + j + 0];
            unsigned long long k1 = sel[sbase + j + 1];
            unsigned long long k2 = sel[sbase + j + 2];
            unsigned long long k3 = sel[sbase + j + 3];
            unsigned long long k4 = sel[sbase + j + 4];
            unsigned long long k5 = sel[sbase + j + 5];
            unsigned long long k6 = sel[sbase + j + 6];
            unsigned long long k7 = sel[sbase + j + 7];
            bigger += (k0 > key) + (k1 > key) + (k2 > key) + (k3 > key)
                    + (k4 > key) + (k5 > key) + (k6 > key) + (k7 > key);
        }
        for (; j < c; ++j) bigger += (sel[sbase + j] > key) ? 1u : 0u;
        unsigned pos = sbase + bigger;
        if (pos < KK) idxout[b * KK + pos] = (int)(~(unsigned)key);
    }
}

// ============ Kernel 2: gather + GEMM1 (C->MID) + BN partials + origins ============
#define KT 64
__global__ __launch_bounds__(256) void gemm1_kernel(const float* __restrict__ feats,
                                                    const float* __restrict__ points,
                                                    const float* __restrict__ w1,
                                                    const int* __restrict__ idx,
                                                    float* __restrict__ h_out,
                                                    float* __restrict__ psum,
                                                    float* __restrict__ psq,
                                                    float* __restrict__ outOrig) {
    __shared__ __align__(16) float w1s[MIDC][68];   // 34.8 KB
    __shared__ __align__(16) float fs[KT][68];      // 17.4 KB
    __shared__ int kidx[KT];
    __shared__ float redS[16][MIDC];                // 8 KB
    __shared__ float redQ[16][MIDC];                // 8 KB

    int t = threadIdx.x;
    int b = blockIdx.x >> 6;                  // K/KT = 64 tiles per batch
    int k0 = (blockIdx.x & 63) * KT;

    if (t < KT) kidx[t] = idx[b * KK + k0 + t];
    __syncthreads();

    if (t < KT * 3) {                         // gather origins
        int k = t / 3, o = t % 3;
        outOrig[(size_t)(b * KK + k0 + k) * 3 + o] =
            points[((size_t)b * NN + kidx[k]) * 3 + o];
    }

    int tm = t & 15;        // 16 m-groups
    int tk = t >> 4;        // 16 k-groups
    float acc[4][8] = {};

    for (int c0 = 0; c0 < CC; c0 += 64) {
        for (int e = t; e < MIDC * 64; e += 256) {       // stage w1 chunk (coalesced)
            int m = e >> 6, c = e & 63;
            w1s[m][c] = w1[m * CC + c0 + c];
        }
        for (int e = t; e < KT * 64; e += 256) {         // gather feats: lanes -> consecutive k
            int k = e & 63, c = e >> 6;
            fs[k][c] = feats[((size_t)b * CC + c0 + c) * NN + kidx[k]];
        }
        __syncthreads();
#pragma unroll
        for (int c = 0; c < 64; c += 4) {
            float4 av[4], wv[8];
#pragma unroll
            for (int i = 0; i < 4; i++) av[i] = *reinterpret_cast<const float4*>(&fs[tk + 16 * i][c]);
#pragma unroll
            for (int j = 0; j < 8; j++) wv[j] = *reinterpret_cast<const float4*>(&w1s[tm + 16 * j][c]);
#pragma unroll
            for (int i = 0; i < 4; i++)
#pragma unroll
                for (int j = 0; j < 8; j++) {
                    acc[i][j] += av[i].x * wv[j].x;
                    acc[i][j] += av[i].y * wv[j].y;
                    acc[i][j] += av[i].z * wv[j].z;
                    acc[i][j] += av[i].w * wv[j].w;
                }
        }
        __syncthreads();
    }

    // write h + per-thread BN partials
    float ps[8] = {}, pq[8] = {};
#pragma unroll
    for (int i = 0; i < 4; i++) {
        int k = tk + 16 * i;
#pragma unroll
        for (int j = 0; j < 8; j++) {
            int m = tm + 16 * j;
            float v = acc[i][j];
            h_out[(size_t)(b * KK + k0 + k) * MIDC + m] = v;
            ps[j] += v;
            pq[j] += v * v;
        }
    }
#pragma unroll
    for (int j = 0; j < 8; j++) { redS[tk][tm + 16 * j] = ps[j]; redQ[tk][tm + 16 * j] = pq[j]; }
    __syncthreads();
    if (t < MIDC) {
        float s = 0.f, q = 0.f;
#pragma unroll
        for (int r = 0; r < 16; r++) { s += redS[r][t]; q += redQ[r][t]; }
        psum[blockIdx.x * MIDC + t] = s;
        psq[blockIdx.x * MIDC + t] = q;
    }
}

// ============ Kernel 3: finalize BN stats -> scale/bias ============
__global__ __launch_bounds__(512) void bnstat_kernel(const float* __restrict__ psum,
                                                     const float* __restrict__ psq,
                                                     const float* __restrict__ gamma,
                                                     const float* __restrict__ beta,
                                                     float* __restrict__ sb) {
    __shared__ float rs[4][MIDC];
    __shared__ float rq[4][MIDC];
    int m = threadIdx.x & 127, g = threadIdx.x >> 7;
    float s = 0.f, q = 0.f;
    for (int blk = g; blk < 256; blk += 4) {
        s += psum[blk * MIDC + m];
        q += psq[blk * MIDC + m];
    }
    rs[g][m] = s; rq[g][m] = q;
    __syncthreads();
    if (threadIdx.x < MIDC) {
        float S = rs[0][m] + rs[1][m] + rs[2][m] + rs[3][m];
        float Q = rq[0][m] + rq[1][m] + rq[2][m] + rq[3][m];
        const float inv = 1.0f / (float)(BB * KK);
        float mean = S * inv;
        float var = Q * inv - mean * mean;
        float scale = gamma[m] * rsqrtf(var + 1e-5f);
        sb[m] = scale;
        sb[MIDC + m] = beta[m] - mean * scale;
    }
}

// ============ Kernel 4: BN+ReLU+GEMM2(128->3)+clamp+add ============
__global__ __launch_bounds__(256) void out_kernel(const float* __restrict__ h,
                                                  const float* __restrict__ sb,
                                                  const float* __restrict__ w2,
                                                  const float* __restrict__ lim,
                                                  const float* __restrict__ orig,
                                                  float* __restrict__ preds,
                                                  float* __restrict__ offs) {
    int tid = blockIdx.x * 256 + threadIdx.x;
    int bk = tid >> 6;                // one wave per (b,k)
    int lane = tid & 63;
    const float* hp = h + (size_t)bk * MIDC;
    float h0 = hp[lane], h1 = hp[lane + 64];
    float y0 = fmaxf(h0 * sb[lane] + sb[MIDC + lane], 0.0f);
    float y1 = fmaxf(h1 * sb[lane + 64] + sb[MIDC + 64 + lane], 0.0f);
    float p0 = y0 * w2[lane]       + y1 * w2[lane + 64];
    float p1 = y0 * w2[128 + lane] + y1 * w2[192 + lane];
    float p2 = y0 * w2[256 + lane] + y1 * w2[320 + lane];
#pragma unroll
    for (int off = 32; off > 0; off >>= 1) {
        p0 += __shfl_xor(p0, off);
        p1 += __shfl_xor(p1, off);
        p2 += __shfl_xor(p2, off);
    }
    if (lane < 3) {
        float o = (lane == 0) ? p0 : ((lane == 1) ? p1 : p2);
        float L = lim[lane];
        float limited = fminf(fmaxf(o, -L), L);
        preds[bk * 3 + lane] = orig[bk * 3 + lane] + limited;
        offs[bk * 3 + lane] = o;
    }
}

// ============ launch ============
extern "C" void kernel_launch(void* const* d_in, const int* in_sizes, int n_in,
                              void* d_out, int out_size, void* d_ws, size_t ws_size,
                              hipStream_t stream) {
    const float* points   = (const float*)d_in[0];
    const float* features = (const float*)d_in[1];
    const float* cls      = (const float*)d_in[2];
    const float* w1       = (const float*)d_in[3];
    const float* gamma    = (const float*)d_in[4];
    const float* beta     = (const float*)d_in[5];
    const float* w2       = (const float*)d_in[6];
    const float* lim      = (const float*)d_in[7];

    float* out   = (float*)d_out;
    float* preds = out;                       // (B,K,3)
    float* orig  = out + BB * KK * 3;         // (B,K,3)
    float* offs  = out + 2 * BB * KK * 3;     // (B,K,3)

    float* wsf = (float*)d_ws;
    int*   idxw = (int*)wsf;                               // B*K
    float* h    = wsf + BB * KK;                           // B*K*MID
    float* psum = h + (size_t)BB * KK * MIDC;              // 256*MID
    float* psq  = psum + 256 * MIDC;                       // 256*MID
    float* sb   = psq + 256 * MIDC;                        // 2*MID

    select_kernel<<<BB, 1024, 0, stream>>>(cls, idxw);
    gemm1_kernel<<<BB * (KK / KT), 256, 0, stream>>>(features, points, w1, idxw, h, psum, psq, orig);
    bnstat_kernel<<<1, 512, 0, stream>>>(psum, psq, gamma, beta, sb);
    out_kernel<<<(BB * KK * 64) / 256, 256, 0, stream>>>(h, sb, w2, lim, orig, preds, offs);
}

// Round 7
// 144.811 us; speedup vs baseline: 1.6644x; 1.1739x over previous
//
#include <hip/hip_runtime.h>

// Problem constants
#define BB 4
#define NN 65536
#define CC 256
#define KK 4096
#define MIDC 128

// ============ Kernel 1: fused score + exact top-K + sorted-order emit ============
// 15-bit fine bins (sign+8exp+6mant of order-preserving key map), packed 2xu16 per
// u32 (64KB LDS). Histogram -> threshold bin + rankbase window; candidates compacted
// grouped-by-bin; exact within-bin rank via broadcast LDS loop. Then a 65536-bit
// mask + prefix-popcount (reusing hist32 LDS) converts the top-k set into ascending
// index order: sidx[rank]=n, kpos[rank]=topk position. GEMM consumes sorted order
// (monotonic gather); outputs are scattered back via kpos.
#define FW 16384      // u32 words = 32768 fine bins
#define WIN 4096      // rankbase/cnt window above threshold bin
#define SELC 6144     // candidate buffer
__global__ __launch_bounds__(1024) void select_kernel(const float* __restrict__ cls,
                                                      int* __restrict__ sidx,
                                                      int* __restrict__ kpos) {
    __shared__ unsigned hist32[FW];            // 64 KB (later: mask/wps/karr)
    __shared__ unsigned long long sel[SELC];   // 48 KB
    __shared__ unsigned rb[WIN];               // 16 KB
    __shared__ unsigned cnt[WIN];              // 16 KB
    __shared__ unsigned ts[1024];              // 4 KB
    __shared__ int tinfo[2];

    int b = blockIdx.x;
    int t = threadIdx.x;
    const float4* cb4 = reinterpret_cast<const float4*>(cls + (size_t)b * NN * 3);

    for (int i = t; i < FW; i += 1024) hist32[i] = 0u;
    for (int i = t; i < WIN; i += 1024) { rb[i] = 0u; cnt[i] = 0u; }
    __syncthreads();

    // P1: keys (4 points/thread/iter, float4 loads) -> packed u16 histogram
    for (int it = 0; it < 16; ++it) {
        int fb = it * 3072 + t * 3;
        float4 v0 = cb4[fb], v1 = cb4[fb + 1], v2 = cb4[fb + 2];
        float m[4];
        m[0] = fmaxf(fmaxf(v0.x, v0.y), v0.z);
        m[1] = fmaxf(fmaxf(v0.w, v1.x), v1.y);
        m[2] = fmaxf(fmaxf(v1.z, v1.w), v2.x);
        m[3] = fmaxf(fmaxf(v2.y, v2.z), v2.w);
#pragma unroll
        for (int j = 0; j < 4; j++) {
            unsigned u = __float_as_uint(m[j]);
            u = (u & 0x80000000u) ? ~u : (u | 0x80000000u);
            atomicAdd(&hist32[u >> 18], ((u >> 17) & 1u) ? 0x10000u : 1u);
        }
    }
    __syncthreads();

    // P2a: unpack 32 fine-bin counts/thread, suffix scan -> threshold bin
    unsigned hloc[32];
    int base = t * 16;
    unsigned s32 = 0;
#pragma unroll
    for (int w = 0; w < 16; w++) {
        unsigned word = hist32[base + w];
        hloc[2 * w] = word & 0xFFFFu;
        hloc[2 * w + 1] = word >> 16;
        s32 += (word & 0xFFFFu) + (word >> 16);
    }
    ts[t] = s32;
    __syncthreads();
    for (int off = 1; off < 1024; off <<= 1) {
        unsigned v = ts[t] + ((t + off) < 1024 ? ts[t + off] : 0u);
        __syncthreads();
        ts[t] = v;
        __syncthreads();
    }
    {
        unsigned above = ts[t] - s32;          // keys in bins owned by threads > t
#pragma unroll
        for (int i = 31; i >= 0; i--) {
            unsigned h = hloc[i];
            if ((int)above < KK && (int)(above + h) >= KK) {
                tinfo[0] = t * 32 + i;
                tinfo[1] = (int)(above + h);   // total candidates
            }
            above += h;
        }
    }
    __syncthreads();
    int tbin = tinfo[0];

    // P2b: rankbase for window bins [tbin, tbin+WIN-1); top window slot merges rest
    {
        unsigned above = ts[t] - s32;
#pragma unroll
        for (int i = 31; i >= 0; i--) {
            int bin = t * 32 + i;
            int off = bin - tbin;
            if (off >= 0 && off < WIN - 1) rb[off] = above;
            above += hloc[i];
        }
    }
    __syncthreads();

    // hist32 is dead now: zero mask region (words 0..2047 = 65536 bits)
    for (int i = t; i < 2048; i += 1024) hist32[i] = 0u;

    // P3: recompute keys, compact candidates grouped by (windowed) bin
    for (int it = 0; it < 16; ++it) {
        int fb = it * 3072 + t * 3;
        float4 v0 = cb4[fb], v1 = cb4[fb + 1], v2 = cb4[fb + 2];
        float m[4];
        m[0] = fmaxf(fmaxf(v0.x, v0.y), v0.z);
        m[1] = fmaxf(fmaxf(v0.w, v1.x), v1.y);
        m[2] = fmaxf(fmaxf(v1.z, v1.w), v2.x);
        m[3] = fmaxf(fmaxf(v2.y, v2.z), v2.w);
#pragma unroll
        for (int j = 0; j < 4; j++) {
            unsigned u = __float_as_uint(m[j]);
            u = (u & 0x80000000u) ? ~u : (u | 0x80000000u);
            int off = (int)(u >> 17) - tbin;
            if (off >= 0) {
                if (off > WIN - 1) off = WIN - 1;
                unsigned slot = rb[off] + atomicAdd(&cnt[off], 1u);
                if (slot < SELC) {
                    int n = it * 4096 + t * 4 + j;
                    sel[slot] = ((unsigned long long)u << 32) | (unsigned)(~n);
                }
            }
        }
    }
    __syncthreads();

    // P4: exact within-bin rank -> karr[pos]=n (hist32[4096..8191]) + set mask bit
    int total = min(tinfo[1], SELC);
    for (int s_ = t; s_ < total; s_ += 1024) {
        unsigned long long key = sel[s_];
        int off = (int)(key >> 49) - tbin;
        if (off > WIN - 1) off = WIN - 1;
        unsigned sbase = rb[off];
        unsigned c = min(cnt[off], (unsigned)SELC - sbase);
        unsigned bigger = 0;
        unsigned j = 0;
        for (; j + 8 <= c; j += 8) {
            unsigned long long k0 = sel[sbase + j + 0];
            unsigned long long k1 = sel[sbase + j + 1];
            unsigned long long k2 = sel[sbase + j + 2];
            unsigned long long k3 = sel[sbase + j + 3];
            unsigned long long k4 = sel[sbase + j + 4];
            unsigned long long k5 = sel[sbase + j + 5];
            unsigned long long k6 = sel[sbase + j + 6];
            unsigned long long k7 = sel[sbase + j + 7];
            bigger += (k0 > key) + (k1 > key) + (k2 > key) + (k3 > key)
                    + (k4 > key) + (k5 > key) + (k6 > key) + (k7 > key);
        }
        for (; j < c; ++j) bigger += (sel[sbase + j] > key) ? 1u : 0u;
        unsigned pos = sbase + bigger;
        if (pos < KK) {
            unsigned n = ~((unsigned)key);
            hist32[4096 + pos] = n;                      // karr
            atomicOr(&hist32[n >> 5], 1u << (n & 31));   // mask
        }
    }
    __syncthreads();

    // P5: prefix popcount over 2048 mask words (2 words/thread) -> wps[2048..4095]
    unsigned pc0 = __popc(hist32[2 * t]);
    unsigned pc1 = __popc(hist32[2 * t + 1]);
    ts[t] = pc0 + pc1;
    __syncthreads();
    for (int off = 1; off < 1024; off <<= 1) {
        unsigned v = ts[t] + ((t >= off) ? ts[t - off] : 0u);
        __syncthreads();
        ts[t] = v;
        __syncthreads();
    }
    {
        unsigned excl = (t > 0) ? ts[t - 1] : 0u;
        hist32[2048 + 2 * t] = excl;
        hist32[2048 + 2 * t + 1] = excl + pc0;
    }
    __syncthreads();

    // P6: emit ascending-index order + topk position
    for (int pos = t; pos < KK; pos += 1024) {
        unsigned n = hist32[4096 + pos];
        unsigned rank = hist32[2048 + (n >> 5)] +
                        __popc(hist32[n >> 5] & ((1u << (n & 31)) - 1u));
        sidx[b * KK + rank] = (int)n;
        kpos[b * KK + rank] = pos;
    }
}

// ============ Kernel 2: sorted gather + GEMM1 (C->MID) + BN partials ============
#define KT 64
__global__ __launch_bounds__(256) void gemm1_kernel(const float* __restrict__ feats,
                                                    const float* __restrict__ w1,
                                                    const int* __restrict__ sidx,
                                                    float* __restrict__ h_out,
                                                    float* __restrict__ psum,
                                                    float* __restrict__ psq) {
    __shared__ __align__(16) float w1s[MIDC][68];   // 34.8 KB
    __shared__ __align__(16) float fs[KT][68];      // 17.4 KB
    __shared__ int kidx[KT];
    __shared__ float redS[16][MIDC];                // 8 KB
    __shared__ float redQ[16][MIDC];                // 8 KB

    int t = threadIdx.x;
    int b = blockIdx.x >> 6;                  // K/KT = 64 tiles per batch
    int k0 = (blockIdx.x & 63) * KT;

    if (t < KT) kidx[t] = sidx[b * KK + k0 + t];
    __syncthreads();

    int tm = t & 15;        // 16 m-groups
    int tk = t >> 4;        // 16 k-groups
    float acc[4][8] = {};

    for (int c0 = 0; c0 < CC; c0 += 64) {
        for (int e = t; e < MIDC * 64; e += 256) {       // stage w1 chunk (coalesced)
            int m = e >> 6, c = e & 63;
            w1s[m][c] = w1[m * CC + c0 + c];
        }
        for (int e = t; e < KT * 64; e += 256) {         // monotonic gather:
            int k = e & 63, c = e >> 6;                  // lanes = consecutive sorted k
            fs[k][c] = feats[((size_t)b * CC + c0 + c) * NN + kidx[k]];
        }
        __syncthreads();
#pragma unroll
        for (int c = 0; c < 64; c += 4) {
            float4 av[4], wv[8];
#pragma unroll
            for (int i = 0; i < 4; i++) av[i] = *reinterpret_cast<const float4*>(&fs[tk + 16 * i][c]);
#pragma unroll
            for (int j = 0; j < 8; j++) wv[j] = *reinterpret_cast<const float4*>(&w1s[tm + 16 * j][c]);
#pragma unroll
            for (int i = 0; i < 4; i++)
#pragma unroll
                for (int j = 0; j < 8; j++) {
                    acc[i][j] += av[i].x * wv[j].x;
                    acc[i][j] += av[i].y * wv[j].y;
                    acc[i][j] += av[i].z * wv[j].z;
                    acc[i][j] += av[i].w * wv[j].w;
                }
        }
        __syncthreads();
    }

    // write h (sorted order) + per-thread BN partials
    float ps[8] = {}, pq[8] = {};
#pragma unroll
    for (int i = 0; i < 4; i++) {
        int k = tk + 16 * i;
#pragma unroll
        for (int j = 0; j < 8; j++) {
            int m = tm + 16 * j;
            float v = acc[i][j];
            h_out[(size_t)(b * KK + k0 + k) * MIDC + m] = v;
            ps[j] += v;
            pq[j] += v * v;
        }
    }
#pragma unroll
    for (int j = 0; j < 8; j++) { redS[tk][tm + 16 * j] = ps[j]; redQ[tk][tm + 16 * j] = pq[j]; }
    __syncthreads();
    if (t < MIDC) {
        float s = 0.f, q = 0.f;
#pragma unroll
        for (int r = 0; r < 16; r++) { s += redS[r][t]; q += redQ[r][t]; }
        psum[blockIdx.x * MIDC + t] = s;
        psq[blockIdx.x * MIDC + t] = q;
    }
}

// ============ Kernel 3: finalize BN stats -> scale/bias ============
__global__ __launch_bounds__(512) void bnstat_kernel(const float* __restrict__ psum,
                                                     const float* __restrict__ psq,
                                                     const float* __restrict__ gamma,
                                                     const float* __restrict__ beta,
                                                     float* __restrict__ sb) {
    __shared__ float rs[4][MIDC];
    __shared__ float rq[4][MIDC];
    int m = threadIdx.x & 127, g = threadIdx.x >> 7;
    float s = 0.f, q = 0.f;
    for (int blk = g; blk < 256; blk += 4) {
        s += psum[blk * MIDC + m];
        q += psq[blk * MIDC + m];
    }
    rs[g][m] = s; rq[g][m] = q;
    __syncthreads();
    if (threadIdx.x < MIDC) {
        float S = rs[0][m] + rs[1][m] + rs[2][m] + rs[3][m];
        float Q = rq[0][m] + rq[1][m] + rq[2][m] + rq[3][m];
        const float inv = 1.0f / (float)(BB * KK);
        float mean = S * inv;
        float var = Q * inv - mean * mean;
        float scale = gamma[m] * rsqrtf(var + 1e-5f);
        sb[m] = scale;
        sb[MIDC + m] = beta[m] - mean * scale;
    }
}

// ============ Kernel 4: BN+ReLU+GEMM2(128->3)+clamp+add, scatter to kpos ============
__global__ __launch_bounds__(256) void out_kernel(const float* __restrict__ h,
                                                  const float* __restrict__ sb,
                                                  const float* __restrict__ w2,
                                                  const float* __restrict__ lim,
                                                  const int* __restrict__ sidx,
                                                  const int* __restrict__ kpos,
                                                  const float* __restrict__ points,
                                                  float* __restrict__ preds,
                                                  float* __restrict__ orig,
                                                  float* __restrict__ offs) {
    int tid = blockIdx.x * 256 + threadIdx.x;
    int bk = tid >> 6;                // sorted slot: b*KK + s
    int lane = tid & 63;
    int b = bk >> 12;                 // KK == 4096
    const float* hp = h + (size_t)bk * MIDC;
    float h0 = hp[lane], h1 = hp[lane + 64];
    float y0 = fmaxf(h0 * sb[lane] + sb[MIDC + lane], 0.0f);
    float y1 = fmaxf(h1 * sb[lane + 64] + sb[MIDC + 64 + lane], 0.0f);
    float p0 = y0 * w2[lane]       + y1 * w2[lane + 64];
    float p1 = y0 * w2[128 + lane] + y1 * w2[192 + lane];
    float p2 = y0 * w2[256 + lane] + y1 * w2[320 + lane];
#pragma unroll
    for (int off = 32; off > 0; off >>= 1) {
        p0 += __shfl_xor(p0, off);
        p1 += __shfl_xor(p1, off);
        p2 += __shfl_xor(p2, off);
    }
    if (lane < 3) {
        int kp = kpos[bk];
        int n = sidx[bk];
        float o = (lane == 0) ? p0 : ((lane == 1) ? p1 : p2);
        float L = lim[lane];
        float limited = fminf(fmaxf(o, -L), L);
        float pt = points[((size_t)b * NN + n) * 3 + lane];
        size_t ob = (size_t)(b * KK + kp) * 3 + lane;
        orig[ob] = pt;
        preds[ob] = pt + limited;
        offs[ob] = o;
    }
}

// ============ launch ============
extern "C" void kernel_launch(void* const* d_in, const int* in_sizes, int n_in,
                              void* d_out, int out_size, void* d_ws, size_t ws_size,
                              hipStream_t stream) {
    const float* points   = (const float*)d_in[0];
    const float* features = (const float*)d_in[1];
    const float* cls      = (const float*)d_in[2];
    const float* w1       = (const float*)d_in[3];
    const float* gamma    = (const float*)d_in[4];
    const float* beta     = (const float*)d_in[5];
    const float* w2       = (const float*)d_in[6];
    const float* lim      = (const float*)d_in[7];

    float* out   = (float*)d_out;
    float* preds = out;                       // (B,K,3)
    float* orig  = out + BB * KK * 3;         // (B,K,3)
    float* offs  = out + 2 * BB * KK * 3;     // (B,K,3)

    float* wsf = (float*)d_ws;
    int*   sidx = (int*)wsf;                               // B*K
    int*   kposp = (int*)(wsf + BB * KK);                  // B*K
    float* h    = wsf + 2 * BB * KK;                       // B*K*MID
    float* psum = h + (size_t)BB * KK * MIDC;              // 256*MID
    float* psq  = psum + 256 * MIDC;                       // 256*MID
    float* sb   = psq + 256 * MIDC;                        // 2*MID

    select_kernel<<<BB, 1024, 0, stream>>>(cls, sidx, kposp);
    gemm1_kernel<<<BB * (KK / KT), 256, 0, stream>>>(features, w1, sidx, h, psum, psq);
    bnstat_kernel<<<1, 512, 0, stream>>>(psum, psq, gamma, beta, sb);
    out_kernel<<<(BB * KK * 64) / 256, 256, 0, stream>>>(h, sb, w2, lim, sidx, kposp,
                                                         points, preds, orig, offs);
}